// Round 2
// baseline (371.520 us; speedup 1.0000x reference)
//
#include <hip/hip_runtime.h>

// Problem geometry (fixed by reference)
constexpr int Bc = 4, Cc = 16, Dd = 64, Hh = 64, Ww = 64, Gg = 5;
constexpr int W4       = Ww / 4;            // 16 float4 per row
constexpr int HW4      = Hh * Ww / 4;       // 1024 float4 per plane
constexpr int SPATIAL4 = Dd * Hh * Ww / 4;  // 65536 float4 per (b,c) channel
constexpr int NTASKS   = Bc * Cc * SPATIAL4; // 4,194,304 float4 tasks

__device__ __forceinline__ float4 f4_zero() { return make_float4(0.f, 0.f, 0.f, 0.f); }

__global__ __launch_bounds__(256) void perc3d_kernel(const float* __restrict__ in,
                                                     float* __restrict__ out) {
    const int idx = blockIdx.x * 256 + threadIdx.x;   // float4 index into input
    // Decompose: idx = ((b*16 + c) * 65536) + d*1024 + h*16 + w4
    const int s  = idx & (SPATIAL4 - 1);
    const int bc = idx >> 16;
    const int w4 = s & (W4 - 1);
    const int h  = (s >> 4) & (Hh - 1);
    const int d  = s >> 10;

    const float4* __restrict__ in4 = (const float4*)in;

    const float4 c0 = in4[idx];
    const float4 xp = (d < Dd - 1) ? in4[idx + HW4] : f4_zero();  // state[d+1]
    const float4 xm = (d > 0)      ? in4[idx - HW4] : f4_zero();  // state[d-1]
    const float4 yp = (h < Hh - 1) ? in4[idx + W4]  : f4_zero();  // state[h+1]
    const float4 ym = (h > 0)      ? in4[idx - W4]  : f4_zero();  // state[h-1]

    // W-axis neighbors via cross-lane shuffle: 16 consecutive lanes = one W-row.
    // Lane's left scalar = previous lane's c0.w; right scalar = next lane's c0.x.
    const float left_raw  = __shfl_up(c0.w, 1, 16);
    const float right_raw = __shfl_down(c0.x, 1, 16);
    const float left  = (w4 > 0)      ? left_raw  : 0.f;  // zero-pad at w==0
    const float right = (w4 < W4 - 1) ? right_raw : 0.f;  // zero-pad at w==63

    // z-axis (W) shifted vectors, in-register
    const float4 zp = make_float4(c0.y, c0.z, c0.w, right);  // state[w+1]
    const float4 zm = make_float4(left, c0.x, c0.y, c0.z);   // state[w-1]

    float4 nsum, gx, gy, gz;
    nsum.x = xp.x + xm.x + yp.x + ym.x + zp.x + zm.x;
    nsum.y = xp.y + xm.y + yp.y + ym.y + zp.y + zm.y;
    nsum.z = xp.z + xm.z + yp.z + ym.z + zp.z + zm.z;
    nsum.w = xp.w + xm.w + yp.w + ym.w + zp.w + zm.w;
    gx.x = xp.x - xm.x;  gx.y = xp.y - xm.y;  gx.z = xp.z - xm.z;  gx.w = xp.w - xm.w;
    gy.x = yp.x - ym.x;  gy.y = yp.y - ym.y;  gy.z = yp.z - ym.z;  gy.w = yp.w - ym.w;
    gz.x = zp.x - zm.x;  gz.y = zp.y - zm.y;  gz.z = zp.z - zm.z;  gz.w = zp.w - zm.w;

    // Output: channel co = c*G + g, layout [B, C*G, D, H, W]
    const int b = bc >> 4;
    const int c = bc & (Cc - 1);
    float4* __restrict__ out4 = (float4*)out;
    const int obase = (b * Cc * Gg + c * Gg) * SPATIAL4 + s;  // max ~21M, fits int

    out4[obase]                = c0;    // identity
    out4[obase + 1 * SPATIAL4] = nsum;  // 6-neighbor sum
    out4[obase + 2 * SPATIAL4] = gx;
    out4[obase + 3 * SPATIAL4] = gy;
    out4[obase + 4 * SPATIAL4] = gz;
}

extern "C" void kernel_launch(void* const* d_in, const int* in_sizes, int n_in,
                              void* d_out, int out_size, void* d_ws, size_t ws_size,
                              hipStream_t stream) {
    const float* state = (const float*)d_in[0];
    float* out = (float*)d_out;
    const int nblocks = NTASKS / 256;  // 16384
    perc3d_kernel<<<nblocks, 256, 0, stream>>>(state, out);
}